// Round 1
// baseline (243.521 us; speedup 1.0000x reference)
//
#include <hip/hip_runtime.h>

// RoPE3D encoder: generate cos/sin tables for (T=32, H=64, W=64), DIM=192.
// Output layout: [cos (N*192 floats)] ++ [sin (N*192 floats)], float32.
// Pure write-bound: 201.3 MB output, no input reads (x only sets dtype).

#define T_FRAMES 32
#define HGT 64
#define WID 64
#define NPOS (T_FRAMES * HGT * WID)   // 131072
#define DIM 192
// log2(10000)/32
#define NEG_C (-0.41524101186092027f)

__global__ __launch_bounds__(256) void rope3d_kernel(float* __restrict__ out) {
    // One thread per float4-group: i in [0, NPOS*48)
    const unsigned int i = blockIdx.x * 256u + threadIdx.x;
    const unsigned int r = i / 48u;            // position row
    const unsigned int c = i - r * 48u;        // float4 column
    const unsigned int j0 = c * 4u;            // feature start (multiple of 4)

    // position decode: r = ((t*64)+h)*64 + w, all power-of-2
    const unsigned int t = r >> 12;
    const unsigned int h = (r >> 6) & 63u;
    const unsigned int w = r & 63u;

    // axis is constant across the 4 features (boundaries at 64/128 are %4==0)
    const unsigned int axis = j0 >> 6;
    const float pos = (float)(axis == 0 ? w : (axis == 1 ? h : t));

    float4 cv, sv;
    float* cvp = &cv.x;
    float* svp = &sv.x;
#pragma unroll
    for (int k = 0; k < 4; ++k) {
        const unsigned int j = j0 + (unsigned int)k;
        const unsigned int inner = j & 31u;    // segment-local freq index
        const float freq = __builtin_exp2f((float)inner * NEG_C);
        const float ang = pos * freq;
        float s, cc;
        __sincosf(ang, &s, &cc);
        cvp[k] = cc;
        svp[k] = s;
    }

    const size_t base = (size_t)r * DIM + j0;
    float4* outc = (float4*)(out + base);
    float4* outs = (float4*)(out + (size_t)NPOS * DIM + base);
    *outc = cv;
    *outs = sv;
}

extern "C" void kernel_launch(void* const* d_in, const int* in_sizes, int n_in,
                              void* d_out, int out_size, void* d_ws, size_t ws_size,
                              hipStream_t stream) {
    (void)d_in; (void)in_sizes; (void)n_in; (void)d_ws; (void)ws_size; (void)out_size;
    float* out = (float*)d_out;
    const unsigned int total4 = NPOS * 48u;           // 6,291,456 threads
    const unsigned int blocks = total4 / 256u;        // 24,576 blocks, exact
    rope3d_kernel<<<blocks, 256, 0, stream>>>(out);
}

// Round 2
// 243.091 us; speedup vs baseline: 1.0018x; 1.0018x over previous
//
#include <hip/hip_runtime.h>

// RoPE3D encoder: cos/sin tables for (T=32, H=64, W=64), DIM=192.
// Output: [cos (N*192 f32)] ++ [sin (N*192 f32)], N = 131072. 192 MiB total.
// Pure write-bound kernel. All transcendentals via raw HW ops in the
// revolution domain (v_exp_f32 / v_fract_f32 / v_sin_f32 / v_cos_f32) —
// no pointer out-args, no addressable locals, so nothing can spill to scratch.

#define NPOS (32 * 64 * 64)   // 131072
#define DIM 192

// -log2(10000)/32  (per-index freq exponent step)
#define NEG_C (-0.41524101186092027f)
// log2(1/(2*pi))  (convert radians-freq to revolutions-freq)
#define LOG2_INV_2PI (-2.6514961294723187f)
// 10000^(-1/32), ^(-2/32), ^(-3/32): ratios between adjacent freqs
#define R1 0.7498942093324559f
#define R2 0.5623413251903491f
#define R3 0.4216965034285822f

__global__ __launch_bounds__(256) void rope3d_kernel(float* __restrict__ out) {
    const unsigned int i = blockIdx.x * 256u + threadIdx.x;   // float4-group id
    const unsigned int r = i / 48u;                           // row (position)
    const unsigned int c = i - r * 48u;                       // float4 col [0,48)

    // position decode (all pow-2): r = ((t*64)+h)*64 + w
    const unsigned int t = r >> 12;
    const unsigned int h = (r >> 6) & 63u;
    const unsigned int w = r & 63u;

    // axis constant across the 4 features (seg boundaries 64/128 are %4==0)
    const unsigned int axis = c >> 4;                         // 0:w 1:h 2:t
    const float pos = (float)(axis == 0 ? w : (axis == 1 ? h : t));

    // base frequency (in revolutions/position) for this thread's first feature
    const unsigned int inner0 = (c * 4u) & 31u;
    const float fr0 = __builtin_exp2f(fmaf((float)inner0, NEG_C, LOG2_INV_2PI));
    const float fr1 = fr0 * R1;
    const float fr2 = fr0 * R2;
    const float fr3 = fr0 * R3;

    // angles in revolutions, range-reduced to [0,1) before v_sin/v_cos
    const float a0 = __builtin_amdgcn_fractf(pos * fr0);
    const float a1 = __builtin_amdgcn_fractf(pos * fr1);
    const float a2 = __builtin_amdgcn_fractf(pos * fr2);
    const float a3 = __builtin_amdgcn_fractf(pos * fr3);

    const float c0 = __builtin_amdgcn_cosf(a0);
    const float c1 = __builtin_amdgcn_cosf(a1);
    const float c2 = __builtin_amdgcn_cosf(a2);
    const float c3 = __builtin_amdgcn_cosf(a3);
    const float s0 = __builtin_amdgcn_sinf(a0);
    const float s1 = __builtin_amdgcn_sinf(a1);
    const float s2 = __builtin_amdgcn_sinf(a2);
    const float s3 = __builtin_amdgcn_sinf(a3);

    const size_t base = (size_t)i * 4u;                       // contiguous
    *(float4*)(out + base) = make_float4(c0, c1, c2, c3);
    *(float4*)(out + (size_t)NPOS * DIM + base) = make_float4(s0, s1, s2, s3);
}

extern "C" void kernel_launch(void* const* d_in, const int* in_sizes, int n_in,
                              void* d_out, int out_size, void* d_ws, size_t ws_size,
                              hipStream_t stream) {
    (void)d_in; (void)in_sizes; (void)n_in; (void)d_ws; (void)ws_size; (void)out_size;
    float* out = (float*)d_out;
    const unsigned int total4 = NPOS * 48u;     // 6,291,456 float4-groups
    const unsigned int blocks = total4 / 256u;  // 24,576 blocks, exact
    rope3d_kernel<<<blocks, 256, 0, stream>>>(out);
}